// Round 3
// baseline (428.364 us; speedup 1.0000x reference)
//
#include <hip/hip_runtime.h>
#include <cstddef>

// Problem constants (B,C,H,W)=(4,3,512,512), E=192, p=2 -> grid 256x256, K=12.
// R7: single-variable experiment vs R6 — plain float4 stores instead of
// __builtin_nontemporal_store. R4/R5/R6 landed within 0.12us of each other
// despite large structural changes => fused kernel is store-drain-bound; the
// nt hint (L2 evict-first) is the only untested store variable. Everything
// else is byte-identical to R6.
constexpr int kH  = 512, kW = 512, kC = 3;
constexpr int kHH = 256, kWW = 256;
constexpr int kN  = kHH * kWW;
constexpr int kE  = 192, kK = 12, kB = 4;

__device__ __forceinline__ float dinvf(int i, int j) {
    // in-degree incl. self-loop: interior 5, edge 4, corner 3 (branch-free)
    const int deg = 1 + (i > 0) + (i < kHH - 1) + (j > 0) + (j < kWW - 1);
    float r = 0.44721359549995794f;            // 1/sqrt(5)
    if (deg == 4) r = 0.5f;                    // 1/sqrt(4)
    if (deg == 3) r = 0.5773502691896258f;     // 1/sqrt(3)
    return r;
}

// M[e][k] = sum_j gcn_w[e][j] * conv_w[j][k]   (conv_w flattened [192][12])
__global__ __launch_bounds__(64) void build_M(const float* __restrict__ gcn_w,
                                              const float* __restrict__ conv_w,
                                              float* __restrict__ M) {
    const int e = blockIdx.x;
    const int lane = threadIdx.x;
    float acc[kK];
#pragma unroll
    for (int k = 0; k < kK; ++k) acc[k] = 0.f;
    for (int j = lane; j < kE; j += 64) {
        const float g = gcn_w[e * kE + j];
        const float4 c0 = *(const float4*)(conv_w + j * kK + 0);
        const float4 c1 = *(const float4*)(conv_w + j * kK + 4);
        const float4 c2 = *(const float4*)(conv_w + j * kK + 8);
        acc[0] += g * c0.x; acc[1] += g * c0.y; acc[2]  += g * c0.z; acc[3]  += g * c0.w;
        acc[4] += g * c1.x; acc[5] += g * c1.y; acc[6]  += g * c1.z; acc[7]  += g * c1.w;
        acc[8] += g * c2.x; acc[9] += g * c2.y; acc[10] += g * c2.z; acc[11] += g * c2.w;
    }
#pragma unroll
    for (int k = 0; k < kK; ++k) {
        float v = acc[k];
#pragma unroll
        for (int off = 32; off > 0; off >>= 1) v += __shfl_down(v, off);
        if (lane == 0) M[e * kK + k] = v;
    }
}

// Fused patchify+aggregate+project: one block = one HALF node row (128 nodes).
// Phase 0: stage x rows 2i-2..2i+3, 3 ch, cols 2*j0-4..2*j0+263 into LDS
//          (aligned float4, halo zero-filled -> phase 1 needs no clipping).
// Phase 1: s_agg[j][k] = dinv-normalized 5-point patch aggregation, pure LDS.
// Phase 2: out = M * agg + bias, M register-resident (4 rows/thread).
constexpr int THREADS = 192;
constexpr int JB      = 128;    // nodes per block
constexpr int XPITCH  = 272;    // 268 staged floats per (c,row), padded

__global__ __launch_bounds__(THREADS, 4) void fused_gcn(
        const float* __restrict__ x, const float* __restrict__ M,
        const float* __restrict__ bias, float* __restrict__ out) {
    __shared__ float s_x[kC * 6 * XPITCH];   // 19584 B
    __shared__ float s_agg[JB][kK];          // 6144 B

    const int t = threadIdx.x;

    // XCD-chunked bijective swizzle (grid 2048 = 8 XCDs x 256): each XCD owns
    // 128 consecutive node rows of one batch -> x window reads stay L2-local.
    const int bid  = (int)blockIdx.x;
    const int wg   = (bid & 7) * 256 + (bid >> 3);
    const int half = wg & 1;
    const int i    = (wg >> 1) & (kHH - 1);
    const int b    = wg >> 9;
    const int j0   = half * JB;

    // Per-thread fixed output channels e..e+3; M rows -> registers.
    const int e4  = t % 48;
    const int sub = t / 48;   // 0..3
    const int e   = e4 * 4;
    float4 mrow[12];
#pragma unroll
    for (int r = 0; r < 12; ++r) mrow[r] = ((const float4*)(M + (size_t)e * kK))[r];
    const float4 bv = *(const float4*)(bias + e);

    // ---- Phase 0: 18 (c,row) segments x 67 aligned float4 = 1206 slots
    const int g0 = 2 * j0 - 4;    // leftmost staged float col (may be <0)
    const int r0 = 2 * i - 2;     // topmost staged pixel row  (may be <0)
#pragma unroll
    for (int q = 0; q < 7; ++q) {
        const int s = t + q * THREADS;
        if (s < 18 * 67) {
            const int cr = s / 67, f = s - cr * 67;
            const int c = cr / 6, row = cr - c * 6;
            const int rg = r0 + row;
            const int gc = g0 + f * 4;
            float4 v = make_float4(0.f, 0.f, 0.f, 0.f);
            if (rg >= 0 && rg < kH && gc >= 0 && gc + 3 < kW)
                v = *(const float4*)(x + ((size_t)(b * kC + c) * kH + rg) * kW + gc);
            *(float4*)&s_x[(c * 6 + row) * XPITCH + f * 4] = v;
        }
    }
    __syncthreads();

    // ---- Phase 1: 1536 entries = 8/thread, idx = j*12+k; zero halos -> no ifs
#pragma unroll
    for (int q = 0; q < 8; ++q) {
        const int idx = t + q * THREADS;
        const int j   = idx / kK;
        const int k   = idx - j * kK;
        const int c = k >> 2, u = (k >> 1) & 1, v = k & 1;
        const int jg = j0 + j;
        const int cc = 2 * j + v + 4;          // center col in stage coords
        const float* sc = &s_x[(c * 6) * XPITCH];
        const float pc = sc[(u + 2) * XPITCH + cc];
        const float pu = sc[(u    ) * XPITCH + cc];      // zero rows at i==0
        const float pd = sc[(u + 4) * XPITCH + cc];      // zero rows at i==255
        const float pl = sc[(u + 2) * XPITCH + cc - 2];  // zero cols at jg==0
        const float pr = sc[(u + 2) * XPITCH + cc + 2];  // zero cols at jg==255
        const float dc = dinvf(i, jg);
        float s2 = dc * pc
                 + dinvf(i - 1, jg) * pu
                 + dinvf(i + 1, jg) * pd
                 + dinvf(i, jg - 1) * pl
                 + dinvf(i, jg + 1) * pr;
        s_agg[j][k] = dc * s2;
    }
    __syncthreads();

    // ---- Phase 2: project 12 -> 192, contiguous 98 KB store per block
    float* outb = out + ((size_t)b * kN + (size_t)i * kWW + j0) * kE + e;
#pragma unroll 4
    for (int it = 0; it < JB / 4; ++it) {
        const int nl = it * 4 + sub;
        const float4 a0 = *((const float4*)&s_agg[nl][0]);
        const float4 a1 = *((const float4*)&s_agg[nl][4]);
        const float4 a2 = *((const float4*)&s_agg[nl][8]);
        float4 acc;
#pragma unroll
        for (int r = 0; r < 4; ++r) {
            const float4 m0 = mrow[r * 3 + 0];
            const float4 m1 = mrow[r * 3 + 1];
            const float4 m2 = mrow[r * 3 + 2];
            float s = ((const float*)&bv)[r];
            s += m0.x * a0.x + m0.y * a0.y + m0.z * a0.z + m0.w * a0.w;
            s += m1.x * a1.x + m1.y * a1.y + m1.z * a1.z + m1.w * a1.w;
            s += m2.x * a2.x + m2.y * a2.y + m2.z * a2.z + m2.w * a2.w;
            ((float*)&acc)[r] = s;
        }
        *(float4*)(outb + (size_t)nl * kE) = acc;
    }
}

extern "C" void kernel_launch(void* const* d_in, const int* in_sizes, int n_in,
                              void* d_out, int out_size, void* d_ws, size_t ws_size,
                              hipStream_t stream) {
    const float* x      = (const float*)d_in[0];  // [4,3,512,512]
    const float* conv_w = (const float*)d_in[1];  // [192,3,2,2] -> [192][12]
    const float* gcn_w  = (const float*)d_in[2];  // [192,192]
    const float* gcn_b  = (const float*)d_in[3];  // [192]
    float* out = (float*)d_out;                   // [4, 65536, 192] fp32
    float* M   = (float*)d_ws;                    // 2304 floats (9216 B)

    build_M<<<kE, 64, 0, stream>>>(gcn_w, conv_w, M);
    fused_gcn<<<kB * kHH * 2, THREADS, 0, stream>>>(x, M, gcn_b, out);
}

// Round 4
// 223.707 us; speedup vs baseline: 1.9148x; 1.9148x over previous
//
#include <hip/hip_runtime.h>
#include <cstddef>

// Problem constants (B,C,H,W)=(4,3,512,512), E=192, p=2 -> grid 256x256, K=12.
// R8: redo R7's plain-store experiment UNCONFOUNDED. R7's 428us regression was
// self-inflicted: float4-class acc written via taken address defeated SROA ->
// VGPR_Count=64 (mrow spilled to scratch) -> ~560MB of scratch TCC traffic.
// Phase 2 is now pure clang ext_vector (element-insert only, no address taken)
// with a PLAIN vector store. Single variable vs R6 (nt store, fused ~64us,
// ~3.3 TB/s drain): does the plain full-line store path hit the fill kernel's
// 6.4 TB/s (FETCH stays small), or does it RFO?
constexpr int kH  = 512, kW = 512, kC = 3;
constexpr int kHH = 256, kWW = 256;
constexpr int kN  = kHH * kWW;
constexpr int kE  = 192, kK = 12, kB = 4;

typedef float f4 __attribute__((ext_vector_type(4)));

__device__ __forceinline__ float dinvf(int i, int j) {
    // in-degree incl. self-loop: interior 5, edge 4, corner 3 (branch-free)
    const int deg = 1 + (i > 0) + (i < kHH - 1) + (j > 0) + (j < kWW - 1);
    float r = 0.44721359549995794f;            // 1/sqrt(5)
    if (deg == 4) r = 0.5f;                    // 1/sqrt(4)
    if (deg == 3) r = 0.5773502691896258f;     // 1/sqrt(3)
    return r;
}

// M[e][k] = sum_j gcn_w[e][j] * conv_w[j][k]   (conv_w flattened [192][12])
__global__ __launch_bounds__(64) void build_M(const float* __restrict__ gcn_w,
                                              const float* __restrict__ conv_w,
                                              float* __restrict__ M) {
    const int e = blockIdx.x;
    const int lane = threadIdx.x;
    float acc[kK];
#pragma unroll
    for (int k = 0; k < kK; ++k) acc[k] = 0.f;
    for (int j = lane; j < kE; j += 64) {
        const float g = gcn_w[e * kE + j];
        const f4 c0 = *(const f4*)(conv_w + j * kK + 0);
        const f4 c1 = *(const f4*)(conv_w + j * kK + 4);
        const f4 c2 = *(const f4*)(conv_w + j * kK + 8);
        acc[0] += g * c0[0]; acc[1] += g * c0[1]; acc[2]  += g * c0[2]; acc[3]  += g * c0[3];
        acc[4] += g * c1[0]; acc[5] += g * c1[1]; acc[6]  += g * c1[2]; acc[7]  += g * c1[3];
        acc[8] += g * c2[0]; acc[9] += g * c2[1]; acc[10] += g * c2[2]; acc[11] += g * c2[3];
    }
#pragma unroll
    for (int k = 0; k < kK; ++k) {
        float v = acc[k];
#pragma unroll
        for (int off = 32; off > 0; off >>= 1) v += __shfl_down(v, off);
        if (lane == 0) M[e * kK + k] = v;
    }
}

// Fused patchify+aggregate+project: one block = one HALF node row (128 nodes).
// Phase 0: stage x rows 2i-2..2i+3, 3 ch, cols 2*j0-4..2*j0+263 into LDS
//          (aligned float4, halo zero-filled -> phase 1 needs no clipping).
// Phase 1: s_agg[j][k] = dinv-normalized 5-point patch aggregation, pure LDS.
// Phase 2: out = M * agg + bias, M register-resident (4 rows/thread),
//          ext_vector only (no address taken -> no scratch), PLAIN f4 stores.
constexpr int THREADS = 192;
constexpr int JB      = 128;    // nodes per block
constexpr int XPITCH  = 272;    // 268 staged floats per (c,row), padded

__global__ __launch_bounds__(THREADS, 4) void fused_gcn(
        const float* __restrict__ x, const float* __restrict__ M,
        const float* __restrict__ bias, float* __restrict__ out) {
    __shared__ float s_x[kC * 6 * XPITCH];   // 19584 B
    __shared__ float s_agg[JB][kK];          // 6144 B

    const int t = threadIdx.x;

    // XCD-chunked bijective swizzle (grid 2048 = 8 XCDs x 256): each XCD owns
    // 128 consecutive node rows of one batch -> x window reads stay L2-local.
    const int bid  = (int)blockIdx.x;
    const int wg   = (bid & 7) * 256 + (bid >> 3);
    const int half = wg & 1;
    const int i    = (wg >> 1) & (kHH - 1);
    const int b    = wg >> 9;
    const int j0   = half * JB;

    // Per-thread fixed output channels e..e+3; M rows -> registers.
    const int e4  = t % 48;
    const int sub = t / 48;   // 0..3
    const int e   = e4 * 4;
    f4 mrow[12];
#pragma unroll
    for (int r = 0; r < 12; ++r) mrow[r] = ((const f4*)(M + (size_t)e * kK))[r];
    const f4 bv = *(const f4*)(bias + e);

    // ---- Phase 0: 18 (c,row) segments x 67 aligned float4 = 1206 slots
    const int g0 = 2 * j0 - 4;    // leftmost staged float col (may be <0)
    const int r0 = 2 * i - 2;     // topmost staged pixel row  (may be <0)
#pragma unroll
    for (int q = 0; q < 7; ++q) {
        const int s = t + q * THREADS;
        if (s < 18 * 67) {
            const int cr = s / 67, f = s - cr * 67;
            const int c = cr / 6, row = cr - c * 6;
            const int rg = r0 + row;
            const int gc = g0 + f * 4;
            f4 v = (f4)(0.f);
            if (rg >= 0 && rg < kH && gc >= 0 && gc + 3 < kW)
                v = *(const f4*)(x + ((size_t)(b * kC + c) * kH + rg) * kW + gc);
            *(f4*)&s_x[(c * 6 + row) * XPITCH + f * 4] = v;
        }
    }
    __syncthreads();

    // ---- Phase 1: 1536 entries = 8/thread, idx = j*12+k; zero halos -> no ifs
#pragma unroll
    for (int q = 0; q < 8; ++q) {
        const int idx = t + q * THREADS;
        const int j   = idx / kK;
        const int k   = idx - j * kK;
        const int c = k >> 2, u = (k >> 1) & 1, v = k & 1;
        const int jg = j0 + j;
        const int cc = 2 * j + v + 4;          // center col in stage coords
        const float* sc = &s_x[(c * 6) * XPITCH];
        const float pc = sc[(u + 2) * XPITCH + cc];
        const float pu = sc[(u    ) * XPITCH + cc];      // zero rows at i==0
        const float pd = sc[(u + 4) * XPITCH + cc];      // zero rows at i==255
        const float pl = sc[(u + 2) * XPITCH + cc - 2];  // zero cols at jg==0
        const float pr = sc[(u + 2) * XPITCH + cc + 2];  // zero cols at jg==255
        const float dc = dinvf(i, jg);
        float s2 = dc * pc
                 + dinvf(i - 1, jg) * pu
                 + dinvf(i + 1, jg) * pd
                 + dinvf(i, jg - 1) * pl
                 + dinvf(i, jg + 1) * pr;
        s_agg[j][k] = dc * s2;
    }
    __syncthreads();

    // ---- Phase 2: project 12 -> 192, contiguous 98 KB store per block
    float* outb = out + ((size_t)b * kN + (size_t)i * kWW + j0) * kE + e;
#pragma unroll 4
    for (int it = 0; it < JB / 4; ++it) {
        const int nl = it * 4 + sub;
        const f4 a0 = *((const f4*)&s_agg[nl][0]);
        const f4 a1 = *((const f4*)&s_agg[nl][4]);
        const f4 a2 = *((const f4*)&s_agg[nl][8]);
        f4 acc;
#pragma unroll
        for (int r = 0; r < 4; ++r) {
            const f4 m0 = mrow[r * 3 + 0];
            const f4 m1 = mrow[r * 3 + 1];
            const f4 m2 = mrow[r * 3 + 2];
            float s = bv[r];
            s += m0[0] * a0[0] + m0[1] * a0[1] + m0[2] * a0[2] + m0[3] * a0[3];
            s += m1[0] * a1[0] + m1[1] * a1[1] + m1[2] * a1[2] + m1[3] * a1[3];
            s += m2[0] * a2[0] + m2[1] * a2[1] + m2[2] * a2[2] + m2[3] * a2[3];
            acc[r] = s;
        }
        *(f4*)(outb + (size_t)nl * kE) = acc;   // plain store: L2/L3-buffered
    }
}

extern "C" void kernel_launch(void* const* d_in, const int* in_sizes, int n_in,
                              void* d_out, int out_size, void* d_ws, size_t ws_size,
                              hipStream_t stream) {
    const float* x      = (const float*)d_in[0];  // [4,3,512,512]
    const float* conv_w = (const float*)d_in[1];  // [192,3,2,2] -> [192][12]
    const float* gcn_w  = (const float*)d_in[2];  // [192,192]
    const float* gcn_b  = (const float*)d_in[3];  // [192]
    float* out = (float*)d_out;                   // [4, 65536, 192] fp32
    float* M   = (float*)d_ws;                    // 2304 floats (9216 B)

    build_M<<<kE, 64, 0, stream>>>(gcn_w, conv_w, M);
    fused_gcn<<<kB * kHH * 2, THREADS, 0, stream>>>(x, M, gcn_b, out);
}

// Round 6
// 222.299 us; speedup vs baseline: 1.9270x; 1.0063x over previous
//
#include <hip/hip_runtime.h>
#include <cstddef>

// Problem constants (B,C,H,W)=(4,3,512,512), E=192, p=2 -> grid 256x256, K=12.
// R9 (resubmit; previous run died to container infra failure, not the kernel).
// Two-adjacent-row blocks. Each block stages 8 pixel rows once (rows 2q, 2q+1
// share 4 of them), then does {agg, project+store} for both node rows.
// x fetch 40->26 MB, half the per-block prologues, M-register load amortized.
// Store path unchanged from R8's win: plain f4 stores, pure ext_vector phase 2
// (no address taken -> no scratch; R7's 428us was SROA-defeat spill).
constexpr int kH  = 512, kW = 512, kC = 3;
constexpr int kHH = 256, kWW = 256;
constexpr int kN  = kHH * kWW;
constexpr int kE  = 192, kK = 12, kB = 4;

typedef float f4 __attribute__((ext_vector_type(4)));

__device__ __forceinline__ float dinvf(int i, int j) {
    // in-degree incl. self-loop: interior 5, edge 4, corner 3 (branch-free)
    const int deg = 1 + (i > 0) + (i < kHH - 1) + (j > 0) + (j < kWW - 1);
    float r = 0.44721359549995794f;            // 1/sqrt(5)
    if (deg == 4) r = 0.5f;                    // 1/sqrt(4)
    if (deg == 3) r = 0.5773502691896258f;     // 1/sqrt(3)
    return r;
}

// M[e][k] = sum_j gcn_w[e][j] * conv_w[j][k]   (conv_w flattened [192][12])
__global__ __launch_bounds__(64) void build_M(const float* __restrict__ gcn_w,
                                              const float* __restrict__ conv_w,
                                              float* __restrict__ M) {
    const int e = blockIdx.x;
    const int lane = threadIdx.x;
    float acc[kK];
#pragma unroll
    for (int k = 0; k < kK; ++k) acc[k] = 0.f;
    for (int j = lane; j < kE; j += 64) {
        const float g = gcn_w[e * kE + j];
        const f4 c0 = *(const f4*)(conv_w + j * kK + 0);
        const f4 c1 = *(const f4*)(conv_w + j * kK + 4);
        const f4 c2 = *(const f4*)(conv_w + j * kK + 8);
        acc[0] += g * c0[0]; acc[1] += g * c0[1]; acc[2]  += g * c0[2]; acc[3]  += g * c0[3];
        acc[4] += g * c1[0]; acc[5] += g * c1[1]; acc[6]  += g * c1[2]; acc[7]  += g * c1[3];
        acc[8] += g * c2[0]; acc[9] += g * c2[1]; acc[10] += g * c2[2]; acc[11] += g * c2[3];
    }
#pragma unroll
    for (int k = 0; k < kK; ++k) {
        float v = acc[k];
#pragma unroll
        for (int off = 32; off > 0; off >>= 1) v += __shfl_down(v, off);
        if (lane == 0) M[e * kK + k] = v;
    }
}

// One block = node rows (2q, 2q+1), half h (128 nodes each).
// Phase 0 : stage pixel rows 2*i0-2 .. 2*i0+5 (8 rows x 3 ch x 268 cols),
//           halo zero-filled -> later phases need no clipping.
// Per tile: phase 1 (agg into s_agg, pure LDS) ; phase 2 (project+store).
constexpr int THREADS = 192;
constexpr int JB      = 128;    // nodes per tile
constexpr int XPITCH  = 272;    // 268 staged floats per (c,row), padded

__global__ __launch_bounds__(THREADS, 4) void fused_gcn(
        const float* __restrict__ x, const float* __restrict__ M,
        const float* __restrict__ bias, float* __restrict__ out) {
    __shared__ float s_x[kC * 8 * XPITCH];   // 26112 B
    __shared__ float s_agg[JB][kK];          // 6144 B

    const int t = threadIdx.x;

    // XCD-chunked bijective swizzle (grid 1024 = 8 XCDs x 128): each XCD owns
    // 64 consecutive double-rows of one batch -> x reads stay L2-local.
    const int bid = (int)blockIdx.x;
    const int wg  = (bid & 7) * 128 + (bid >> 3);
    const int h   = wg & 1;
    const int q   = (wg >> 1) & 127;
    const int b   = wg >> 8;
    const int i0  = 2 * q;          // first of the two node rows
    const int j0  = h * JB;

    // Per-thread fixed output channels e..e+3; M rows -> registers (both tiles).
    const int e4  = t % 48;
    const int sub = t / 48;   // 0..3
    const int e   = e4 * 4;
    f4 mrow[12];
#pragma unroll
    for (int r = 0; r < 12; ++r) mrow[r] = ((const f4*)(M + (size_t)e * kK))[r];
    const f4 bv = *(const f4*)(bias + e);

    // ---- Phase 0: 24 (c,row) segments x 67 aligned f4 = 1608 slots
    const int g0 = 2 * j0 - 4;      // leftmost staged float col (may be <0)
    const int r0 = 2 * i0 - 2;      // topmost staged pixel row  (may be <0)
#pragma unroll
    for (int qq = 0; qq < 9; ++qq) {
        const int s = t + qq * THREADS;
        if (s < 24 * 67) {
            const int cr = s / 67, f = s - cr * 67;
            const int c = cr >> 3, row = cr & 7;
            const int rg = r0 + row;
            const int gc = g0 + f * 4;
            f4 v = (f4)(0.f);
            if (rg >= 0 && rg < kH && gc >= 0 && gc + 3 < kW)
                v = *(const f4*)(x + ((size_t)(b * kC + c) * kH + rg) * kW + gc);
            *(f4*)&s_x[(c * 8 + row) * XPITCH + f * 4] = v;
        }
    }
    __syncthreads();

#pragma unroll
    for (int tile = 0; tile < 2; ++tile) {
        const int i     = i0 + tile;
        const int rbase = 2 * tile;     // staged-row offset for this tile

        // ---- Phase 1: 1536 entries = 8/thread; zero halos -> no ifs
#pragma unroll
        for (int qq = 0; qq < 8; ++qq) {
            const int idx = t + qq * THREADS;
            const int j   = idx / kK;
            const int k   = idx - j * kK;
            const int c = k >> 2, u = (k >> 1) & 1, v = k & 1;
            const int jg = j0 + j;
            const int cc = 2 * j + v + 4;          // center col in stage coords
            const float* sc = &s_x[(c * 8 + rbase) * XPITCH];
            const float pc = sc[(u + 2) * XPITCH + cc];
            const float pu = sc[(u    ) * XPITCH + cc];      // zero rows at i==0
            const float pd = sc[(u + 4) * XPITCH + cc];      // zero rows at i==255
            const float pl = sc[(u + 2) * XPITCH + cc - 2];  // zero cols at jg==0
            const float pr = sc[(u + 2) * XPITCH + cc + 2];  // zero cols at jg==255
            const float dc = dinvf(i, jg);
            float s2 = dc * pc
                     + dinvf(i - 1, jg) * pu
                     + dinvf(i + 1, jg) * pd
                     + dinvf(i, jg - 1) * pl
                     + dinvf(i, jg + 1) * pr;
            s_agg[j][k] = dc * s2;
        }
        __syncthreads();

        // ---- Phase 2: project 12 -> 192, contiguous 98 KB store per tile
        float* outb = out + ((size_t)b * kN + (size_t)i * kWW + j0) * kE + e;
#pragma unroll 4
        for (int it = 0; it < JB / 4; ++it) {
            const int nl = it * 4 + sub;
            const f4 a0 = *((const f4*)&s_agg[nl][0]);
            const f4 a1 = *((const f4*)&s_agg[nl][4]);
            const f4 a2 = *((const f4*)&s_agg[nl][8]);
            f4 acc;
#pragma unroll
            for (int r = 0; r < 4; ++r) {
                const f4 m0 = mrow[r * 3 + 0];
                const f4 m1 = mrow[r * 3 + 1];
                const f4 m2 = mrow[r * 3 + 2];
                float s = bv[r];
                s += m0[0] * a0[0] + m0[1] * a0[1] + m0[2] * a0[2] + m0[3] * a0[3];
                s += m1[0] * a1[0] + m1[1] * a1[1] + m1[2] * a1[2] + m1[3] * a1[3];
                s += m2[0] * a2[0] + m2[1] * a2[1] + m2[2] * a2[2] + m2[3] * a2[3];
                acc[r] = s;
            }
            *(f4*)(outb + (size_t)nl * kE) = acc;   // plain store (R8 win)
        }
        __syncthreads();    // s_agg reused by next tile's phase 1
    }
}

extern "C" void kernel_launch(void* const* d_in, const int* in_sizes, int n_in,
                              void* d_out, int out_size, void* d_ws, size_t ws_size,
                              hipStream_t stream) {
    const float* x      = (const float*)d_in[0];  // [4,3,512,512]
    const float* conv_w = (const float*)d_in[1];  // [192,3,2,2] -> [192][12]
    const float* gcn_w  = (const float*)d_in[2];  // [192,192]
    const float* gcn_b  = (const float*)d_in[3];  // [192]
    float* out = (float*)d_out;                   // [4, 65536, 192] fp32
    float* M   = (float*)d_ws;                    // 2304 floats (9216 B)

    build_M<<<kE, 64, 0, stream>>>(gcn_w, conv_w, M);
    fused_gcn<<<kB * (kHH / 2) * 2, THREADS, 0, stream>>>(x, M, gcn_b, out);
}